// Round 4
// baseline (456.080 us; speedup 1.0000x reference)
//
#include <hip/hip_runtime.h>
#include <math.h>

constexpr int kN  = 4096;
constexpr int kFI = 128;
constexpr int kFO = 64;
constexpr int kH  = 4;
constexpr int kHF = 256;   // kH*kFO
constexpr float kNegInf = -1e9f;
constexpr float kLnEps  = 1e-5f;

typedef short bf16x8 __attribute__((ext_vector_type(8)));
typedef float f32x4  __attribute__((ext_vector_type(4)));

__device__ __forceinline__ float lrelu(float x){ return x >= 0.f ? x : 0.2f*x; }

__device__ __forceinline__ float wave_sum(float v){
  #pragma unroll
  for (int s = 32; s > 0; s >>= 1) v += __shfl_xor(v, s, 64);
  return v;
}

__device__ __forceinline__ unsigned short f2bf(float x){
  unsigned u = __float_as_uint(x);
  u = (u + 0x7fffu + ((u >> 16) & 1u)) >> 16;
  return (unsigned short)u;
}
__device__ __forceinline__ unsigned f2bf_pk(float a, float b){
  return (unsigned)f2bf(a) | ((unsigned)f2bf(b) << 16);
}

// ---------------------------------------------------------------------------
// K0: transpose skw [256][128] -> skwT [128][256] so k_proj reads coalesce.
// ---------------------------------------------------------------------------
__global__ __launch_bounds__(256) void k_tr(
    const float* __restrict__ skw, float* __restrict__ skwT)
{
  const int k  = blockIdx.x;      // 0..127
  const int hf = threadIdx.x;     // 0..255
  skwT[k*kHF + hf] = skw[hf*kFI + k];
}

// ---------------------------------------------------------------------------
// K1: proj[h][n][o], ga/gb scores, skip = nodes @ skw^T. 16 nodes/block.
// Both weight streams (pp, skwT) lane-coalesced, L2-resident.
// ---------------------------------------------------------------------------
__global__ __launch_bounds__(256) void k_proj(
    const float* __restrict__ nodes, const float* __restrict__ pp,
    const float* __restrict__ ssrc,  const float* __restrict__ stgt,
    const float* __restrict__ skwT,
    float* __restrict__ proj, float* __restrict__ ga, float* __restrict__ gb,
    float* __restrict__ skipo)
{
  __shared__ float feat[16][kFI];
  const int tid = threadIdx.x;
  const int n0  = blockIdx.x * 16;
  for (int idx = tid; idx < 16*kFI; idx += 256)
    feat[idx >> 7][idx & 127] = nodes[n0*kFI + idx];
  __syncthreads();
  const int h = tid >> 6, o = tid & 63;
  float accP[16], accS[16];
  #pragma unroll
  for (int n = 0; n < 16; ++n){ accP[n] = 0.f; accS[n] = 0.f; }
  for (int k = 0; k < kFI; ++k){
    const float p = pp[(h*kFI + k)*kFO + o];
    const float w = skwT[k*kHF + tid];
    #pragma unroll
    for (int n = 0; n < 16; ++n){
      const float f = feat[n][k];
      accP[n] = fmaf(f, p, accP[n]);
      accS[n] = fmaf(f, w, accS[n]);
    }
  }
  const float sa = ssrc[h*kFO + o];
  const float sb = stgt[h*kFO + o];
  #pragma unroll
  for (int n = 0; n < 16; ++n){
    proj[(h*kN + n0+n)*kFO + o] = accP[n];
    skipo[(n0+n)*kHF + tid]     = accS[n];
    const float va = wave_sum(accP[n] * sa);
    const float vb = wave_sum(accP[n] * sb);
    if (o == 0){ ga[h*kN + n0+n] = va; gb[h*kN + n0+n] = vb; }
  }
}

// ---------------------------------------------------------------------------
// K2: column pass + row LN stats. grid (4 j-tiles, 512 i-strips of 8) x 256.
// S[h][j] = sum_i exp(leaky(a_i+b_j)+m_ij) (unstabilized, safe: scores
// bounded; -1e9 underflows to 0 exactly like the stabilized ref).
// ---------------------------------------------------------------------------
__global__ __launch_bounds__(256) void k_colsum(
    const float* __restrict__ degm, const float* __restrict__ bondm,
    const float* __restrict__ ga,   const float* __restrict__ gb,
    const int* __restrict__ cutp,
    float* __restrict__ S, float* __restrict__ statg,
    float* __restrict__ maskws, int write_mask)
{
  const int j0 = (blockIdx.x * 256 + threadIdx.x) * 4;
  const int lane = threadIdx.x & 63;
  const float cut = (float)cutp[0];
  float4 bv[kH]; f32x4 sv[kH];
  #pragma unroll
  for (int h = 0; h < kH; ++h){
    bv[h] = *(const float4*)&gb[h*kN + j0];
    sv[h] = (f32x4){0.f, 0.f, 0.f, 0.f};
  }
  const int i0 = blockIdx.y * 8;
  for (int ib = 0; ib < 8; ib += 4){
    float4 dg[4], bd[4];
    #pragma unroll
    for (int u = 0; u < 4; ++u){
      const size_t off = (size_t)(i0+ib+u)*kN + j0;
      dg[u] = *(const float4*)&degm[off];
      bd[u] = *(const float4*)&bondm[off];
    }
    #pragma unroll
    for (int u = 0; u < 4; ++u){
      const int i = i0 + ib + u;
      float4 m;
      {
        float w0 = dg[u].x + bd[u].x, w1 = dg[u].y + bd[u].y;
        float w2 = dg[u].z + bd[u].z, w3 = dg[u].w + bd[u].w;
        m.x = w0 > 0.f ? w0 : (bd[u].x > cut ? bd[u].x + w0 : kNegInf);
        m.y = w1 > 0.f ? w1 : (bd[u].y > cut ? bd[u].y + w1 : kNegInf);
        m.z = w2 > 0.f ? w2 : (bd[u].z > cut ? bd[u].z + w2 : kNegInf);
        m.w = w3 > 0.f ? w3 : (bd[u].w > cut ? bd[u].w + w3 : kNegInf);
      }
      if (write_mask) *(float4*)&maskws[(size_t)i*kN + j0] = m;
      float rsum = (m.x + m.y) + (m.z + m.w);
      float rsq  = fmaf(m.x, m.x, fmaf(m.y, m.y, fmaf(m.z, m.z, m.w*m.w)));
      rsum = wave_sum(rsum); rsq = wave_sum(rsq);
      if (lane == 0){
        atomicAdd(&statg[2*i+0], rsum);
        atomicAdd(&statg[2*i+1], rsq);
      }
      #pragma unroll
      for (int h = 0; h < kH; ++h){
        const float a = ga[h*kN + i];
        sv[h][0] += __expf(lrelu(a + bv[h].x) + m.x);
        sv[h][1] += __expf(lrelu(a + bv[h].y) + m.y);
        sv[h][2] += __expf(lrelu(a + bv[h].z) + m.z);
        sv[h][3] += __expf(lrelu(a + bv[h].w) + m.w);
      }
    }
  }
  #pragma unroll
  for (int h = 0; h < kH; ++h){
    atomicAdd(&S[h*kN + j0+0], sv[h][0]);
    atomicAdd(&S[h*kN + j0+1], sv[h][1]);
    atomicAdd(&S[h*kN + j0+2], sv[h][2]);
    atomicAdd(&S[h*kN + j0+3], sv[h][3]);
  }
}

// ---------------------------------------------------------------------------
// K2b: finalize LN stats: statg2[i] = (mu, rsqrt(var+eps))
// ---------------------------------------------------------------------------
__global__ __launch_bounds__(256) void k_stat(
    const float* __restrict__ statg, float* __restrict__ statg2)
{
  const int i = blockIdx.x * 256 + threadIdx.x;
  const float mu  = statg[2*i] * (1.f/kN);
  const float var = statg[2*i+1] * (1.f/kN) - mu*mu;
  statg2[2*i+0] = mu;
  statg2[2*i+1] = rsqrtf(var + kLnEps);
}

// ---------------------------------------------------------------------------
// K2c: pack pS = proj/S into bf16 MFMA B-fragment layout.
// pSpack[h][kb][nt][lane][r] = bf16(pS[h][ kb*32+(lane>>4)*8+r ][ nt*16+(lane&15) ])
// ---------------------------------------------------------------------------
__global__ __launch_bounds__(256) void k_pack(
    const float* __restrict__ proj, const float* __restrict__ S,
    unsigned short* __restrict__ pSpack)
{
  const int t = blockIdx.x * 256 + threadIdx.x;   // 131072 total
  const int L  = t & 63;
  const int nt = (t >> 6) & 3;
  const int kb = (t >> 8) & 127;
  const int h  = t >> 15;
  const int f  = nt*16 + (L & 15);
  const int jb = kb*32 + (L >> 4)*8;
  union { unsigned short s[8]; uint4 v; } u;
  #pragma unroll
  for (int r = 0; r < 8; ++r){
    const int j = jb + r;
    u.s[r] = f2bf(proj[(size_t)(h*kN + j)*kFO + f] / S[h*kN + j]);
  }
  ((uint4*)pSpack)[t] = u.v;
}

// ---------------------------------------------------------------------------
// K3: aggregation via MFMA. grid (kN/16 row-groups, 8 j-eighths) x 256 thr.
// Per 64-col chunk:
//   phase A: 256 threads: one (row, col-quad) each; float4 mask load, 16 exps,
//            bf16 pairs into LDS A-layout, mask_ln float4 written inline.
//   phase B: 4 waves = 4 heads; 2 K-steps x 4 n-tiles mfma_f32_16x16x32_bf16.
// Partial C merged into accg by float atomics.
// ---------------------------------------------------------------------------
__global__ __launch_bounds__(256) void k_aggr(
    const float* __restrict__ degm, const float* __restrict__ bondm,
    const float* __restrict__ maskws, int have_mask,
    const float* __restrict__ ga, const float* __restrict__ gb,
    const int* __restrict__ cutp,
    const unsigned short* __restrict__ pSpack,
    const float* __restrict__ statg2,
    float* __restrict__ accg, float* __restrict__ mlnp)
{
  __shared__ unsigned short ebuf[kH][16][72];   // 9.2 KB (+8 short pad)
  const int tid = threadIdx.x;
  const int w   = tid >> 6;          // phase-B head
  const int L   = tid & 63;
  const int r0  = blockIdx.x * 16;
  const int jq0 = blockIdx.y * 512;
  const int ia  = tid >> 4;          // phase-A row 0..15
  const int jq  = tid & 15;          // phase-A col-quad
  const float cut = (float)cutp[0];

  float av[kH];
  #pragma unroll
  for (int hh = 0; hh < kH; ++hh) av[hh] = ga[hh*kN + r0 + ia];
  const float mu = statg2[2*(r0+ia)+0];
  const float rs = statg2[2*(r0+ia)+1];

  f32x4 acc[4];
  #pragma unroll
  for (int nt = 0; nt < 4; ++nt) acc[nt] = (f32x4){0.f,0.f,0.f,0.f};

  for (int c = 0; c < 8; ++c){
    const int jb = jq0 + c*64;
    // ---- phase A ----
    {
      const int jg = jb + 4*jq;
      const size_t off = (size_t)(r0+ia)*kN + jg;
      float4 m;
      if (have_mask){
        m = *(const float4*)&maskws[off];
      } else {
        const float4 dg = *(const float4*)&degm[off];
        const float4 bd = *(const float4*)&bondm[off];
        float w0 = dg.x + bd.x, w1 = dg.y + bd.y;
        float w2 = dg.z + bd.z, w3 = dg.w + bd.w;
        m.x = w0 > 0.f ? w0 : (bd.x > cut ? bd.x + w0 : kNegInf);
        m.y = w1 > 0.f ? w1 : (bd.y > cut ? bd.y + w1 : kNegInf);
        m.z = w2 > 0.f ? w2 : (bd.z > cut ? bd.z + w2 : kNegInf);
        m.w = w3 > 0.f ? w3 : (bd.w > cut ? bd.w + w3 : kNegInf);
      }
      float4 o;
      o.x = (m.x - mu) * rs;  o.y = (m.y - mu) * rs;
      o.z = (m.z - mu) * rs;  o.w = (m.w - mu) * rs;
      *(float4*)&mlnp[off] = o;
      #pragma unroll
      for (int hh = 0; hh < kH; ++hh){
        const float4 bv = *(const float4*)&gb[hh*kN + jg];
        const float e0 = __expf(lrelu(av[hh] + bv.x) + m.x);
        const float e1 = __expf(lrelu(av[hh] + bv.y) + m.y);
        const float e2 = __expf(lrelu(av[hh] + bv.z) + m.z);
        const float e3 = __expf(lrelu(av[hh] + bv.w) + m.w);
        uint2 u;
        u.x = f2bf_pk(e0, e1);
        u.y = f2bf_pk(e2, e3);
        *(uint2*)&ebuf[hh][ia][4*jq] = u;
      }
    }
    __syncthreads();
    // ---- phase B ----
    {
      const int kb0 = (jb >> 5);
      #pragma unroll
      for (int ks = 0; ks < 2; ++ks){
        const bf16x8 a = *(const bf16x8*)&ebuf[w][L & 15][ks*32 + (L >> 4)*8];
        const int kb = kb0 + ks;
        #pragma unroll
        for (int nt = 0; nt < 4; ++nt){
          const bf16x8 b = *(const bf16x8*)&pSpack[(size_t)(((w*128 + kb)*4 + nt)*64 + L)*8];
          acc[nt] = __builtin_amdgcn_mfma_f32_16x16x32_bf16(a, b, acc[nt], 0, 0, 0);
        }
      }
    }
    __syncthreads();
  }

  // epilogue: C/D layout col=lane&15, row=(lane>>4)*4+reg
  #pragma unroll
  for (int nt = 0; nt < 4; ++nt){
    #pragma unroll
    for (int reg = 0; reg < 4; ++reg){
      const int i = r0 + (L >> 4)*4 + reg;
      const int f = w*64 + nt*16 + (L & 15);
      atomicAdd(&accg[(size_t)i*kHF + f], acc[nt][reg]);
    }
  }
}

// ---------------------------------------------------------------------------
// K4: out = elu(acc + skip)
// ---------------------------------------------------------------------------
__global__ __launch_bounds__(256) void k_out(
    const float* __restrict__ accg, const float* __restrict__ skipo,
    float* __restrict__ outp)
{
  const int idx = blockIdx.x * 256 + threadIdx.x;
  float o = accg[idx] + skipo[idx];
  o = o > 0.f ? o : expm1f(o);
  outp[idx] = o;
}

// ---------------------------------------------------------------------------
extern "C" void kernel_launch(void* const* d_in, const int* in_sizes, int n_in,
                              void* d_out, int out_size, void* d_ws, size_t ws_size,
                              hipStream_t stream)
{
  const float* nodes = (const float*)d_in[0];
  const float* degm  = (const float*)d_in[1];
  const float* bondm = (const float*)d_in[3];
  const float* pp    = (const float*)d_in[4];
  const float* ssrc  = (const float*)d_in[5];
  const float* stgt  = (const float*)d_in[6];
  const float* skw   = (const float*)d_in[7];
  const int*   cutp  = (const int*)d_in[8];

  float* ws    = (float*)d_ws;
  float* proj  = ws;                               // H*N*FO = 1,048,576
  float* ga    = proj + (size_t)kH*kN*kFO;         // 16384
  float* gb    = ga + kH*kN;                       // 16384
  float* S     = gb + kH*kN;                       // 16384
  float* skip  = S + kH*kN;                        // N*HF = 1,048,576
  float* accg  = skip + (size_t)kN*kHF;            // N*HF = 1,048,576
  float* statg = accg + (size_t)kN*kHF;            // 2*N
  float* statg2= statg + 2*kN;                     // 2*N
  float* skwT  = statg2 + 2*kN;                    // 128*256 = 32768
  unsigned short* pSpack = (unsigned short*)(skwT + (size_t)kFI*kHF); // 1,048,576 bf16
  float* mask  = (float*)(pSpack + (size_t)kH*kN*kFO);               // N*N (optional)

  const size_t base_floats = (size_t)kH*kN*kFO + 3*(size_t)kH*kN
                           + 2*(size_t)kN*kHF + 4*kN + (size_t)kFI*kHF
                           + ((size_t)kH*kN*kFO)/2;
  const size_t need_mask = (base_floats + (size_t)kN*kN) * sizeof(float);
  const int have_mask = (ws_size >= need_mask) ? 1 : 0;

  float* outp = (float*)d_out;
  float* mlnp = outp + (size_t)kN*kHF;

  hipMemsetAsync(S, 0, kH*kN*sizeof(float), stream);
  hipMemsetAsync(accg, 0, (size_t)kN*kHF*sizeof(float), stream);
  hipMemsetAsync(statg, 0, 2*kN*sizeof(float), stream);

  k_tr<<<kFI, 256, 0, stream>>>(skw, skwT);
  k_proj<<<kN/16, 256, 0, stream>>>(nodes, pp, ssrc, stgt, skwT, proj, ga, gb, skip);
  k_colsum<<<dim3(kN/1024, kN/8), 256, 0, stream>>>(degm, bondm, ga, gb, cutp,
                                                    S, statg, mask, have_mask);
  k_stat<<<kN/256, 256, 0, stream>>>(statg, statg2);
  k_pack<<<(kH*128*4*64)/256, 256, 0, stream>>>(proj, S, pSpack);
  k_aggr<<<dim3(kN/16, 8), 256, 0, stream>>>(degm, bondm, mask, have_mask,
                                             ga, gb, cutp, pSpack, statg2,
                                             accg, mlnp);
  k_out<<<(kN*kHF)/256, 256, 0, stream>>>(accg, skip, outp);
}

// Round 5
// 333.206 us; speedup vs baseline: 1.3688x; 1.3688x over previous
//
#include <hip/hip_runtime.h>
#include <math.h>

constexpr int kN  = 4096;
constexpr int kFI = 128;
constexpr int kFO = 64;
constexpr int kH  = 4;
constexpr int kHF = 256;   // kH*kFO
constexpr float kNegInf = -1e9f;
constexpr float kLnEps  = 1e-5f;
constexpr int kStrips = 128;   // k_colsum i-strips of 32 rows

typedef short bf16x8 __attribute__((ext_vector_type(8)));
typedef float f32x4  __attribute__((ext_vector_type(4)));

__device__ __forceinline__ float lrelu(float x){ return x >= 0.f ? x : 0.2f*x; }

__device__ __forceinline__ float wave_sum(float v){
  #pragma unroll
  for (int s = 32; s > 0; s >>= 1) v += __shfl_xor(v, s, 64);
  return v;
}

__device__ __forceinline__ unsigned short f2bf(float x){
  unsigned u = __float_as_uint(x);
  u = (u + 0x7fffu + ((u >> 16) & 1u)) >> 16;
  return (unsigned short)u;
}
__device__ __forceinline__ unsigned f2bf_pk(float a, float b){
  return (unsigned)f2bf(a) | ((unsigned)f2bf(b) << 16);
}

// ---------------------------------------------------------------------------
// K0: transpose skw [256][128] -> skwT [128][256] so k_proj reads coalesce.
// ---------------------------------------------------------------------------
__global__ __launch_bounds__(256) void k_tr(
    const float* __restrict__ skw, float* __restrict__ skwT)
{
  const int k  = blockIdx.x;      // 0..127
  const int hf = threadIdx.x;     // 0..255
  skwT[k*kHF + hf] = skw[hf*kFI + k];
}

// ---------------------------------------------------------------------------
// K1: proj[h][n][o], ga/gb scores, skip = nodes @ skw^T. 8 nodes/block,
// 512 blocks (2/CU). k-loop unrolled x4 with hoisted L2 loads.
// ---------------------------------------------------------------------------
__global__ __launch_bounds__(256) void k_proj(
    const float* __restrict__ nodes, const float* __restrict__ pp,
    const float* __restrict__ ssrc,  const float* __restrict__ stgt,
    const float* __restrict__ skwT,
    float* __restrict__ proj, float* __restrict__ ga, float* __restrict__ gb,
    float* __restrict__ skipo)
{
  __shared__ float feat[8][kFI];    // 4 KB
  const int tid = threadIdx.x;
  const int n0  = blockIdx.x * 8;
  for (int idx = tid; idx < 8*kFI; idx += 256)
    feat[idx >> 7][idx & 127] = nodes[n0*kFI + idx];
  __syncthreads();
  const int h = tid >> 6, o = tid & 63;
  float accP[8], accS[8];
  #pragma unroll
  for (int n = 0; n < 8; ++n){ accP[n] = 0.f; accS[n] = 0.f; }
  for (int k0 = 0; k0 < kFI; k0 += 4){
    float p[4], w[4];
    #pragma unroll
    for (int u = 0; u < 4; ++u){
      p[u] = pp[(h*kFI + k0+u)*kFO + o];
      w[u] = skwT[(k0+u)*kHF + tid];
    }
    #pragma unroll
    for (int n = 0; n < 8; ++n){
      const float4 f4 = *(const float4*)&feat[n][k0];
      accP[n] = fmaf(f4.x, p[0], fmaf(f4.y, p[1],
                fmaf(f4.z, p[2], fmaf(f4.w, p[3], accP[n]))));
      accS[n] = fmaf(f4.x, w[0], fmaf(f4.y, w[1],
                fmaf(f4.z, w[2], fmaf(f4.w, w[3], accS[n]))));
    }
  }
  const float sa = ssrc[h*kFO + o];
  const float sb = stgt[h*kFO + o];
  #pragma unroll
  for (int n = 0; n < 8; ++n){
    proj[(h*kN + n0+n)*kFO + o] = accP[n];
    skipo[(n0+n)*kHF + tid]     = accS[n];
    const float va = wave_sum(accP[n] * sa);
    const float vb = wave_sum(accP[n] * sb);
    if (o == 0){ ga[h*kN + n0+n] = va; gb[h*kN + n0+n] = vb; }
  }
}

// ---------------------------------------------------------------------------
// K2: column pass + row LN stat partials. grid (4 j-tiles, 128 strips of 32)
// x 256 thr. S partials -> Spart (NO atomics). Stats: per-thread register
// partials across the strip, one batched ILP wave-reduction at the end
// (atomics only there: 131k total). Unstabilized exp (safe, see R0 analysis).
// ---------------------------------------------------------------------------
__global__ __launch_bounds__(256) void k_colsum(
    const float* __restrict__ degm, const float* __restrict__ bondm,
    const float* __restrict__ ga,   const float* __restrict__ gb,
    const int* __restrict__ cutp,
    float* __restrict__ Spart, float* __restrict__ statg,
    float* __restrict__ maskws, int write_mask)
{
  const int j0 = (blockIdx.x * 256 + threadIdx.x) * 4;
  const int lane = threadIdx.x & 63;
  const float cut = (float)cutp[0];
  float4 bv[kH]; f32x4 sv[kH];
  #pragma unroll
  for (int h = 0; h < kH; ++h){
    bv[h] = *(const float4*)&gb[h*kN + j0];
    sv[h] = (f32x4){0.f, 0.f, 0.f, 0.f};
  }
  float msum[32], msq[32];
  #pragma unroll
  for (int r = 0; r < 32; ++r){ msum[r] = 0.f; msq[r] = 0.f; }

  const int i0 = blockIdx.y * 32;
  for (int ib = 0; ib < 32; ib += 4){
    float4 dg[4], bd[4];
    #pragma unroll
    for (int u = 0; u < 4; ++u){
      const size_t off = (size_t)(i0+ib+u)*kN + j0;
      dg[u] = *(const float4*)&degm[off];
      bd[u] = *(const float4*)&bondm[off];
    }
    #pragma unroll
    for (int u = 0; u < 4; ++u){
      const int i = i0 + ib + u;
      float4 m;
      {
        float w0 = dg[u].x + bd[u].x, w1 = dg[u].y + bd[u].y;
        float w2 = dg[u].z + bd[u].z, w3 = dg[u].w + bd[u].w;
        m.x = w0 > 0.f ? w0 : (bd[u].x > cut ? bd[u].x + w0 : kNegInf);
        m.y = w1 > 0.f ? w1 : (bd[u].y > cut ? bd[u].y + w1 : kNegInf);
        m.z = w2 > 0.f ? w2 : (bd[u].z > cut ? bd[u].z + w2 : kNegInf);
        m.w = w3 > 0.f ? w3 : (bd[u].w > cut ? bd[u].w + w3 : kNegInf);
      }
      if (write_mask) *(float4*)&maskws[(size_t)i*kN + j0] = m;
      msum[ib+u] += (m.x + m.y) + (m.z + m.w);
      msq[ib+u]  += fmaf(m.x, m.x, fmaf(m.y, m.y, fmaf(m.z, m.z, m.w*m.w)));
      #pragma unroll
      for (int h = 0; h < kH; ++h){
        const float a = ga[h*kN + i];
        sv[h][0] += __expf(lrelu(a + bv[h].x) + m.x);
        sv[h][1] += __expf(lrelu(a + bv[h].y) + m.y);
        sv[h][2] += __expf(lrelu(a + bv[h].z) + m.z);
        sv[h][3] += __expf(lrelu(a + bv[h].w) + m.w);
      }
    }
  }
  // S partials: coalesced stores, no atomics
  #pragma unroll
  for (int h = 0; h < kH; ++h)
    *(float4*)&Spart[(size_t)(blockIdx.y*kH + h)*kN + j0] = *(float4*)&sv[h];

  // batched stat reductions (64 independent shuffle chains -> ILP)
  #pragma unroll
  for (int r = 0; r < 32; ++r){
    const float s1 = wave_sum(msum[r]);
    const float s2 = wave_sum(msq[r]);
    if (lane == 0){
      atomicAdd(&statg[2*(i0+r)+0], s1);
      atomicAdd(&statg[2*(i0+r)+1], s2);
    }
  }
}

// ---------------------------------------------------------------------------
// K2b: reduce S partials: S[h][j] = sum_strips Spart[strip][h][j]
// ---------------------------------------------------------------------------
__global__ __launch_bounds__(256) void k_sred(
    const float* __restrict__ Spart, float* __restrict__ S)
{
  const int idx = blockIdx.x * 256 + threadIdx.x;   // 16384
  float s = 0.f;
  for (int p = 0; p < kStrips; ++p) s += Spart[(size_t)p*kH*kN + idx];
  S[idx] = s;
}

// ---------------------------------------------------------------------------
// K2c: finalize LN stats: statg2[i] = (mu, rsqrt(var+eps))
// ---------------------------------------------------------------------------
__global__ __launch_bounds__(256) void k_stat(
    const float* __restrict__ statg, float* __restrict__ statg2)
{
  const int i = blockIdx.x * 256 + threadIdx.x;
  const float mu  = statg[2*i] * (1.f/kN);
  const float var = statg[2*i+1] * (1.f/kN) - mu*mu;
  statg2[2*i+0] = mu;
  statg2[2*i+1] = rsqrtf(var + kLnEps);
}

// ---------------------------------------------------------------------------
// K2d: pack pS = proj/S into bf16 MFMA B-fragment layout.
// pSpack[h][kb][nt][lane][r] = bf16(pS[h][ kb*32+(lane>>4)*8+r ][ nt*16+(lane&15) ])
// ---------------------------------------------------------------------------
__global__ __launch_bounds__(256) void k_pack(
    const float* __restrict__ proj, const float* __restrict__ S,
    unsigned short* __restrict__ pSpack)
{
  const int t = blockIdx.x * 256 + threadIdx.x;   // 131072 total
  const int L  = t & 63;
  const int nt = (t >> 6) & 3;
  const int kb = (t >> 8) & 127;
  const int h  = t >> 15;
  const int f  = nt*16 + (L & 15);
  const int jb = kb*32 + (L >> 4)*8;
  union { unsigned short s[8]; uint4 v; } u;
  #pragma unroll
  for (int r = 0; r < 8; ++r){
    const int j = jb + r;
    u.s[r] = f2bf(proj[(size_t)(h*kN + j)*kFO + f] / S[h*kN + j]);
  }
  ((uint4*)pSpack)[t] = u.v;
}

// ---------------------------------------------------------------------------
// K3: aggregation via MFMA. grid (kN/16 row-groups, 4 j-quarters) x 256 thr.
// Per 64-col chunk: phase A: one (row, col-quad) per thread -> 16 exps,
// bf16 pairs into LDS A-layout (stride 70 shorts: conflict-free b64 halves),
// mask_ln float4 written inline. phase B: 4 waves = 4 heads; 2 K-steps x
// 4 n-tiles of mfma_f32_16x16x32_bf16. Partials -> accpart (NO atomics).
// ---------------------------------------------------------------------------
__global__ __launch_bounds__(256) void k_aggr(
    const float* __restrict__ degm, const float* __restrict__ bondm,
    const float* __restrict__ maskws, int have_mask,
    const float* __restrict__ ga, const float* __restrict__ gb,
    const int* __restrict__ cutp,
    const unsigned short* __restrict__ pSpack,
    const float* __restrict__ statg2,
    float* __restrict__ accpart, float* __restrict__ mlnp)
{
  __shared__ unsigned short ebuf[kH*16*70];   // 8.96 KB
  const int tid = threadIdx.x;
  const int w   = tid >> 6;          // phase-B head
  const int L   = tid & 63;
  const int r0  = blockIdx.x * 16;
  const int jq  = blockIdx.y;
  const int jq0 = jq * 1024;
  const int ia  = tid >> 4;          // phase-A row 0..15
  const int jc  = tid & 15;          // phase-A col-quad
  const float cut = (float)cutp[0];

  float av[kH];
  #pragma unroll
  for (int hh = 0; hh < kH; ++hh) av[hh] = ga[hh*kN + r0 + ia];
  const float mu = statg2[2*(r0+ia)+0];
  const float rs = statg2[2*(r0+ia)+1];

  f32x4 acc[4];
  #pragma unroll
  for (int nt = 0; nt < 4; ++nt) acc[nt] = (f32x4){0.f,0.f,0.f,0.f};

  for (int c = 0; c < 16; ++c){
    const int jb = jq0 + c*64;
    // ---- phase A ----
    {
      const int jg = jb + 4*jc;
      const size_t off = (size_t)(r0+ia)*kN + jg;
      float4 m;
      if (have_mask){
        m = *(const float4*)&maskws[off];
      } else {
        const float4 dg = *(const float4*)&degm[off];
        const float4 bd = *(const float4*)&bondm[off];
        float w0 = dg.x + bd.x, w1 = dg.y + bd.y;
        float w2 = dg.z + bd.z, w3 = dg.w + bd.w;
        m.x = w0 > 0.f ? w0 : (bd.x > cut ? bd.x + w0 : kNegInf);
        m.y = w1 > 0.f ? w1 : (bd.y > cut ? bd.y + w1 : kNegInf);
        m.z = w2 > 0.f ? w2 : (bd.z > cut ? bd.z + w2 : kNegInf);
        m.w = w3 > 0.f ? w3 : (bd.w > cut ? bd.w + w3 : kNegInf);
      }
      float4 o;
      o.x = (m.x - mu) * rs;  o.y = (m.y - mu) * rs;
      o.z = (m.z - mu) * rs;  o.w = (m.w - mu) * rs;
      *(float4*)&mlnp[off] = o;
      #pragma unroll
      for (int hh = 0; hh < kH; ++hh){
        const float4 bv = *(const float4*)&gb[hh*kN + jg];
        const float e0 = __expf(lrelu(av[hh] + bv.x) + m.x);
        const float e1 = __expf(lrelu(av[hh] + bv.y) + m.y);
        const float e2 = __expf(lrelu(av[hh] + bv.z) + m.z);
        const float e3 = __expf(lrelu(av[hh] + bv.w) + m.w);
        uint2 u;
        u.x = f2bf_pk(e0, e1);
        u.y = f2bf_pk(e2, e3);
        *(uint2*)&ebuf[(hh*16 + ia)*70 + 4*jc] = u;
      }
    }
    __syncthreads();
    // ---- phase B ----
    {
      const int kb0 = (jb >> 5);
      #pragma unroll
      for (int ks = 0; ks < 2; ++ks){
        const bf16x8 a = *(const bf16x8*)&ebuf[(w*16 + (L & 15))*70 + ks*32 + (L >> 4)*8];
        const int kb = kb0 + ks;
        #pragma unroll
        for (int nt = 0; nt < 4; ++nt){
          const bf16x8 b = *(const bf16x8*)&pSpack[(size_t)(((w*128 + kb)*4 + nt)*64 + L)*8];
          acc[nt] = __builtin_amdgcn_mfma_f32_16x16x32_bf16(a, b, acc[nt], 0, 0, 0);
        }
      }
    }
    __syncthreads();
  }

  // epilogue: C/D layout col=lane&15, row=(lane>>4)*4+reg -> partial store
  #pragma unroll
  for (int nt = 0; nt < 4; ++nt){
    #pragma unroll
    for (int reg = 0; reg < 4; ++reg){
      const int i = r0 + (L >> 4)*4 + reg;
      const int f = w*64 + nt*16 + (L & 15);
      accpart[((size_t)jq*kN + i)*kHF + f] = acc[nt][reg];
    }
  }
}

// ---------------------------------------------------------------------------
// K4: out = elu(sum_q accpart[q] + skip)
// ---------------------------------------------------------------------------
__global__ __launch_bounds__(256) void k_out(
    const float* __restrict__ accpart, const float* __restrict__ skipo,
    float* __restrict__ outp)
{
  const int idx = blockIdx.x * 256 + threadIdx.x;
  float o = skipo[idx];
  #pragma unroll
  for (int q = 0; q < 4; ++q) o += accpart[(size_t)q*kN*kHF + idx];
  o = o > 0.f ? o : expm1f(o);
  outp[idx] = o;
}

// ---------------------------------------------------------------------------
extern "C" void kernel_launch(void* const* d_in, const int* in_sizes, int n_in,
                              void* d_out, int out_size, void* d_ws, size_t ws_size,
                              hipStream_t stream)
{
  const float* nodes = (const float*)d_in[0];
  const float* degm  = (const float*)d_in[1];
  const float* bondm = (const float*)d_in[3];
  const float* pp    = (const float*)d_in[4];
  const float* ssrc  = (const float*)d_in[5];
  const float* stgt  = (const float*)d_in[6];
  const float* skw   = (const float*)d_in[7];
  const int*   cutp  = (const int*)d_in[8];

  float* ws     = (float*)d_ws;
  float* proj   = ws;                               // 1,048,576
  float* ga     = proj + (size_t)kH*kN*kFO;         // 16384
  float* gb     = ga + kH*kN;                       // 16384
  float* S      = gb + kH*kN;                       // 16384
  float* skip   = S + kH*kN;                        // 1,048,576
  float* statg  = skip + (size_t)kN*kHF;            // 8192
  float* statg2 = statg + 2*kN;                     // 8192
  float* skwT   = statg2 + 2*kN;                    // 32768
  float* accpart= skwT + (size_t)kFI*kHF;           // 4,194,304 (4 x N x HF)
  float* Spart  = accpart;                          // aliases: dead before k_aggr
  unsigned short* pSpack = (unsigned short*)(accpart + (size_t)4*kN*kHF); // 2M bf16
  float* mask   = (float*)(pSpack + (size_t)kH*kN*kFO);                   // N*N

  const size_t base_floats = (size_t)kH*kN*kFO + 3*(size_t)kH*kN
                           + 2*(size_t)kN*kHF + 4*(size_t)kN + (size_t)kFI*kHF
                           + (size_t)4*kN*kHF + ((size_t)kH*kN*kFO)/2;
  const size_t need_mask = (base_floats + (size_t)kN*kN) * sizeof(float);
  const int have_mask = (ws_size >= need_mask) ? 1 : 0;

  float* outp = (float*)d_out;
  float* mlnp = outp + (size_t)kN*kHF;

  hipMemsetAsync(statg, 0, 2*kN*sizeof(float), stream);

  k_tr<<<kFI, 256, 0, stream>>>(skw, skwT);
  k_proj<<<kN/8, 256, 0, stream>>>(nodes, pp, ssrc, stgt, skwT, proj, ga, gb, skip);
  k_colsum<<<dim3(kN/1024, kStrips), 256, 0, stream>>>(degm, bondm, ga, gb, cutp,
                                                       Spart, statg, mask, have_mask);
  k_sred<<<(kH*kN)/256, 256, 0, stream>>>(Spart, S);
  k_stat<<<kN/256, 256, 0, stream>>>(statg, statg2);
  k_pack<<<(kH*128*4*64)/256, 256, 0, stream>>>(proj, S, pSpack);
  k_aggr<<<dim3(kN/16, 4), 256, 0, stream>>>(degm, bondm, mask, have_mask,
                                             ga, gb, cutp, pSpack, statg2,
                                             accpart, mlnp);
  k_out<<<(kN*kHF)/256, 256, 0, stream>>>(accpart, skip, outp);
}